// Round 3
// baseline (393.078 us; speedup 1.0000x reference)
//
#include <hip/hip_runtime.h>
#include <math.h>

// CTC batch cost: B=256, T=256, C=1024, L=32 -> S=65 extended states.
// Round 3: random-gather -> streaming. Read ALL of y_pred coalesced
// (268 MB streams at ~6.5 TB/s; the 33-of-1024 random selection is done
// from LDS where scattered access is cheap). One block (16 waves) per
// batch element; 32 chunks of 8 rows, register-double-buffered staging;
// wave 0 then runs the serial alpha recursion from s_lp.

#define Bt 256
#define Tt 256
#define Ct 1024
#define Lt 32
#define NEGV (-1e30f)
#define EPSV (1e-7f)
#define SLP 34              // padded row stride of s_lp (floats)
#define RPC 8               // rows (timesteps) per chunk
#define NC (Tt / RPC)       // 32 chunks
#define F4PC (RPC * Ct / 4) // 2048 float4 per chunk

__device__ __forceinline__ float lae2(float a, float b) {
    float m = fmaxf(a, b);
    return m + __logf(__expf(a - m) + __expf(b - m));
}
__device__ __forceinline__ float lae3(float a, float b, float c) {
    float m = fmaxf(fmaxf(a, b), c);
    return m + __logf(__expf(a - m) + __expf(b - m) + __expf(c - m));
}

__global__ __launch_bounds__(1024) void ctc_kernel(const int* __restrict__ y_true,
                                                   const float* __restrict__ y_pred,
                                                   float* __restrict__ out) {
    __shared__ float s_lp[Tt * SLP];       // 34816 B
    __shared__ float s_stage[RPC * Ct];    // 32768 B
    __shared__ float s_alpha[66];

    const int b = blockIdx.x;
    const int tid = threadIdx.x;
    const int w = tid >> 6;
    const int lane = tid & 63;
    const int blank = Ct - 1;
    const float4* yp4 = (const float4*)(y_pred + (size_t)b * Tt * Ct);
    const int* lab = y_true + b * Lt;

    // class this lane selects: labels for lanes 0..31, blank for lane 32
    int cls = blank;
    if (lane < 32) cls = lab[lane];

    float4* s_stage4 = (float4*)s_stage;

    // prologue: stage chunk 0
    {
        float4 r0 = yp4[tid];
        float4 r1 = yp4[tid + 1024];
        s_stage4[tid] = r0;
        s_stage4[tid + 1024] = r1;
    }
    __syncthreads();

    for (int c = 0; c < NC; ++c) {
        float4 r0, r1;
        const bool more = (c + 1 < NC);
        if (more) {
            r0 = yp4[(c + 1) * F4PC + tid];
            r1 = yp4[(c + 1) * F4PC + tid + 1024];
        }
        // select chunk c: wave w handles timestep c*8+w, lanes 0..32 pick classes
        if (w < RPC && lane < 33) {
            int t = c * RPC + w;
            s_lp[t * SLP + lane] = __logf(s_stage[w * Ct + cls] + EPSV);
        }
        __syncthreads();
        if (more) {
            s_stage4[tid] = r0;
            s_stage4[tid + 1024] = r1;
            __syncthreads();
        }
    }

    // ---- phase 2: wave 0 runs the alpha recursion ----
    if (w == 0) {
        bool allow = true;
        if (lane >= 1 && lane < 32) {
            int lprev = lab[lane - 1];
            allow = (cls != blank) && (cls != lprev);
        }
        unsigned long long nz = __ballot(lane < 32 && cls != 0);
        int ll = (int)__popcll(nz);

        float a_even, a_odd;
        {
            float le = s_lp[32];                                 // t=0 blank
            float lo = (lane < 32) ? s_lp[lane] : NEGV;          // t=0 labels
            a_even = (lane == 0) ? le : NEGV;
            a_odd  = (lane == 0) ? lo : NEGV;
        }

        #pragma unroll 4
        for (int t = 1; t < Tt; ++t) {
            float le = s_lp[t * SLP + 32];
            float lo = (lane < 32) ? s_lp[t * SLP + lane] : NEGV;
            float po = __shfl_up(a_odd, 1);                      // old a[2i-1]
            if (lane == 0) po = NEGV;
            float ne = le + lae2(a_even, po);
            float no = lo + lae3(a_odd, a_even, allow ? po : NEGV);
            a_even = ne;
            a_odd  = no;
        }

        if (lane < 33) {
            s_alpha[2 * lane] = a_even;
            if (lane < 32) s_alpha[2 * lane + 1] = a_odd;
        }
        __builtin_amdgcn_s_waitcnt(0);
        if (lane == 0) {
            int i1 = 2 * ll;
            int i2 = 2 * ll - 1;
            float v1 = s_alpha[i1];
            float v2 = (i2 >= 0) ? s_alpha[i2] : NEGV;
            out[b] = -lae2(v1, v2);
        }
    }
}

extern "C" void kernel_launch(void* const* d_in, const int* in_sizes, int n_in,
                              void* d_out, int out_size, void* d_ws, size_t ws_size,
                              hipStream_t stream) {
    const int* y_true = (const int*)d_in[0];
    const float* y_pred = (const float*)d_in[1];
    float* out = (float*)d_out;
    (void)in_sizes; (void)n_in; (void)out_size; (void)d_ws; (void)ws_size;
    ctc_kernel<<<Bt, 1024, 0, stream>>>(y_true, y_pred, out);
}

// Round 4
// 373.250 us; speedup vs baseline: 1.0531x; 1.0531x over previous
//
#include <hip/hip_runtime.h>
#include <math.h>

// CTC batch cost: B=256, T=256, C=1024, L=32 -> S=65 extended states.
// Round 4: two-kernel split.
//  K1 (gather): one thread per (b,t,sel) of the 33 needed classes
//    (32 labels + blank) -> scattered 4B load + log -> compact ws[b][t][33].
//    Massive parallelism (33k waves) hides random-load latency; traffic
//    ~31 unique 64B sectors/row ~= 130 MB (vs 268 MB full stream).
//  K2 (recursion): 1 wave per batch element, depth-16 register prefetch
//    pipeline over the compact lp rows; blank broadcast via shfl(lane 32);
//    alpha states in registers (lane i holds states 2i, 2i+1). No LDS.

#define Bt 256
#define Tt 256
#define Ct 1024
#define Lt 32
#define NSEL 33
#define TOTE (Bt * Tt * NSEL)   // 2,162,688 = 8448 * 256
#define NEGV (-1e30f)
#define EPSV (1e-7f)

__device__ __forceinline__ float lae2(float a, float b) {
    float m = fmaxf(a, b);
    return m + __logf(__expf(a - m) + __expf(b - m));
}
__device__ __forceinline__ float lae3(float a, float b, float c) {
    float m = fmaxf(fmaxf(a, b), c);
    return m + __logf(__expf(a - m) + __expf(b - m) + __expf(c - m));
}

// ---- K1: gather the 33 needed log-probs per (b,t) into ws ----
__global__ __launch_bounds__(256) void ctc_gather(const int* __restrict__ y_true,
                                                  const float* __restrict__ y_pred,
                                                  float* __restrict__ ws) {
    unsigned e = blockIdx.x * 256u + threadIdx.x;      // e < TOTE (exact grid)
    unsigned row = e / 33u;                            // b*256 + t
    unsigned j = e - row * 33u;                        // 0..32
    unsigned b = row >> 8;
    int cls = Ct - 1;                                  // blank for j==32
    if (j < 32u) cls = y_true[(b << 5) + j];
    float v = y_pred[((size_t)row << 10) + (unsigned)cls];
    ws[e] = __logf(v + EPSV);
}

// ---- K2: serial alpha recursion per batch element ----
__global__ __launch_bounds__(64) void ctc_rec(const int* __restrict__ y_true,
                                              const float* __restrict__ ws,
                                              float* __restrict__ out) {
    const int b = blockIdx.x;
    const int lane = threadIdx.x;
    const int li = (lane < 33) ? lane : 32;            // clamp (dup loads ok)
    const float* lp = ws + (size_t)b * Tt * NSEL;
    const int* lab = y_true + b * Lt;

    int cls = (lane < 32) ? lab[lane] : (Ct - 1);
    bool allow = true;
    if (lane >= 1 && lane < 32) {
        int lprev = lab[lane - 1];
        allow = (cls != Ct - 1) && (cls != lprev);
    }
    unsigned long long nz = __ballot(lane < 32 && cls != 0);
    int ll = (int)__popcll(nz);

    // depth-16 register prefetch pipeline; group-unrolled so buf[] stays
    // in registers. Group g consumes t = g*16+k while loading group g+1.
    float buf[16];
    #pragma unroll
    for (int k = 0; k < 16; ++k) buf[k] = lp[k * NSEL + li];

    float a_even = NEGV, a_odd = NEGV;
    for (int g = 0; g < 16; ++g) {
        #pragma unroll
        for (int k = 0; k < 16; ++k) {
            float cur = buf[k];
            // refill with t+16; for g==15 this reads past this b's region
            // (still inside the ~1GB ws allocation) and is never consumed.
            buf[k] = lp[((unsigned)((g + 1) * 16 + k)) * NSEL + li];
            float le = __shfl(cur, 32);                 // blank, broadcast
            float lo = (lane < 32) ? cur : NEGV;        // label log-prob
            if (k == 0 && g == 0) {
                a_even = (lane == 0) ? le : NEGV;
                a_odd  = (lane == 0) ? lo : NEGV;
            } else {
                float po = __shfl_up(a_odd, 1);         // old a[2i-1]
                if (lane == 0) po = NEGV;
                float ne = le + lae2(a_even, po);
                float no = lo + lae3(a_odd, a_even, allow ? po : NEGV);
                a_even = ne;
                a_odd  = no;
            }
        }
    }

    // loss = -logaddexp(alpha[2*ll], alpha[2*ll-1])
    float v1 = __shfl(a_even, ll);                      // even state 2*ll
    float v2 = (ll >= 1) ? __shfl(a_odd, ll - 1) : NEGV;// odd state 2*ll-1
    if (lane == 0) out[b] = -lae2(v1, v2);
}

extern "C" void kernel_launch(void* const* d_in, const int* in_sizes, int n_in,
                              void* d_out, int out_size, void* d_ws, size_t ws_size,
                              hipStream_t stream) {
    const int* y_true = (const int*)d_in[0];
    const float* y_pred = (const float*)d_in[1];
    float* out = (float*)d_out;
    float* ws = (float*)d_ws;
    (void)in_sizes; (void)n_in; (void)out_size; (void)ws_size;
    ctc_gather<<<TOTE / 256, 256, 0, stream>>>(y_true, y_pred, ws);
    ctc_rec<<<Bt, 64, 0, stream>>>(y_true, ws, out);
}